// Round 2
// baseline (142.998 us; speedup 1.0000x reference)
//
#include <hip/hip_runtime.h>
#include <stdint.h>

typedef unsigned short u16;
typedef __attribute__((ext_vector_type(8))) short short8;
typedef __attribute__((ext_vector_type(4))) float f32x4;

#define S_LEN 2048
#define HID   1024
#define QKV_LD 3072
#define M_ROWS 8192   // B*S

__device__ __forceinline__ u16 f2bf(float f) {
  unsigned u = __float_as_uint(f);
  unsigned r = (u + 0x7fffu + ((u >> 16) & 1u)) >> 16;
  return (u16)r;
}

__device__ __forceinline__ void gload16(const u16* g, u16* l) {
  __builtin_amdgcn_global_load_lds(
      (const __attribute__((address_space(1))) unsigned int*)(g),
      (__attribute__((address_space(3))) unsigned int*)(l),
      16, 0, 0);
}

template<int N_VM> __device__ __forceinline__ void vmwait() {
  if constexpr (N_VM == 6)      asm volatile("s_waitcnt vmcnt(6)" ::: "memory");
  else if constexpr (N_VM == 3) asm volatile("s_waitcnt vmcnt(3)" ::: "memory");
  else                          asm volatile("s_waitcnt vmcnt(0)" ::: "memory");
}
__device__ __forceinline__ void wgbar() {
  asm volatile("" ::: "memory");
  __builtin_amdgcn_s_barrier();
  asm volatile("" ::: "memory");
}

// ---------------- pack kernels ----------------
__global__ __launch_bounds__(256) void cvt_f32_to_bf16(
    const float* __restrict__ in, u16* __restrict__ out, int n) {
  int i = (blockIdx.x * 256 + threadIdx.x) * 8;
  if (i + 8 > n) return;
  float4 a = *(const float4*)(in + i);
  float4 b = *(const float4*)(in + i + 4);
  u16 t[8];
  t[0] = f2bf(a.x); t[1] = f2bf(a.y); t[2] = f2bf(a.z); t[3] = f2bf(a.w);
  t[4] = f2bf(b.x); t[5] = f2bf(b.y); t[6] = f2bf(b.z); t[7] = f2bf(b.w);
  *(short8*)(out + i) = *(short8*)t;
}

// in: f32 [K][N] row-major; out: bf16 [N][K] row-major
__global__ __launch_bounds__(256) void transpose_to_bf16(
    const float* __restrict__ in, u16* __restrict__ out, int K, int N) {
  __shared__ float tile[32][33];
  int tx = threadIdx.x & 31, ty = threadIdx.x >> 5;
  int n0 = blockIdx.x * 32, k0 = blockIdx.y * 32;
#pragma unroll
  for (int i = 0; i < 32; i += 8)
    tile[ty + i][tx] = in[(size_t)(k0 + ty + i) * N + n0 + tx];
  __syncthreads();
#pragma unroll
  for (int i = 0; i < 32; i += 8)
    out[(size_t)(n0 + ty + i) * K + k0 + tx] = f2bf(tile[tx][ty + i]);
}

__global__ __launch_bounds__(256) void pack_bias(
    const float* __restrict__ bq, const float* __restrict__ bk,
    const float* __restrict__ bv, float* __restrict__ out) {
  int i = blockIdx.x * 256 + threadIdx.x;
  if (i >= 3072) return;
  out[i] = (i < 1024) ? bq[i] : (i < 2048) ? bk[i - 1024] : bv[i - 2048];
}

// ---------------- pipelined GEMM: C = A[M,1024] * Bt[N,1024]^T + bias ----
// BM=128 x BN=256 tile, 8 waves (2Mx4N), K slabs of 32, ring-4 LDS buffers,
// prefetch distance 3 slabs, counted vmcnt(6) at slab boundaries (never 0
// in steady state). XOR swizzle slot^=(row>>1)&3 on both staged source and
// frag reads -> 2 lanes/bank (free) on ds_read_b128.
// Race-freedom: slab s+3 writes buf[(s-1)&3] whose readers finished at the
// end-of-slab-(s-1) barrier; per-thread vmcnt + barrier => slab s fully
// landed for ALL threads before any thread reads it.
template<int OUT_BF16>
__global__ __launch_bounds__(512, 2) void gemm_p(
    const u16* __restrict__ A, const u16* __restrict__ Bt,
    const float* __restrict__ bias, void* __restrict__ Cout,
    int M, int N) {
  constexpr int K = 1024, NSLAB = 32;
  constexpr int BM = 128, BN = 256;
  constexpr int ASL = BM * 32;            // u16 per A-slab (4096)
  constexpr int BUFSZ = (BM + BN) * 32;   // u16 per ring slot (12288)
  __shared__ __align__(16) u16 smem[4 * BUFSZ];  // 96 KiB

  const int tid = threadIdx.x;
  const int wave = tid >> 6, lane = tid & 63;
  const int qlane = lane & 15, kgrp = lane >> 4;
  const int wm = wave >> 2, wn = wave & 3;
  const int nbn = N >> 8;
  int wg = blockIdx.x;
  const int cpx = (int)gridDim.x >> 3;    // grid % 8 == 0 by construction
  wg = (wg & 7) * cpx + (wg >> 3);
  const int bm = wg / nbn, bn = wg % nbn;

  // per-thread staging source offsets (inverse-swizzled global source)
  size_t ga0, gb0, gb1;
  {
    int c = tid;                          // A chunk (1/thread, 128 rows)
    int row = c >> 2, sp = c & 3;
    ga0 = (size_t)(bm * BM + row) * K + (size_t)((sp ^ ((row >> 1) & 3)) * 8);
  }
  {
    int c = tid;                          // B chunk 0
    int row = c >> 2, sp = c & 3;
    gb0 = (size_t)(bn * BN + row) * K + (size_t)((sp ^ ((row >> 1) & 3)) * 8);
    c = tid + 512;                        // B chunk 1
    row = c >> 2; sp = c & 3;
    gb1 = (size_t)(bn * BN + row) * K + (size_t)((sp ^ ((row >> 1) & 3)) * 8);
  }

  auto stage = [&](int t) {
    const int bb = (t & 3) * BUFSZ;
    const int kt = t * 32;
    gload16(A + ga0 + kt,  (u16*)&smem[bb + (wave * 64) * 8]);
    gload16(Bt + gb0 + kt, (u16*)&smem[bb + ASL + (wave * 64) * 8]);
    gload16(Bt + gb1 + kt, (u16*)&smem[bb + ASL + (wave * 64 + 512) * 8]);
  };

  f32x4 acc[4][4] = {};

  auto comp = [&](int s) {
    const u16* Ab = &smem[(s & 3) * BUFSZ];
    const u16* Bb = Ab + ASL;
    short8 af[4], bf[4];
#pragma unroll
    for (int mf = 0; mf < 4; ++mf) {
      int r = wm * 64 + mf * 16 + qlane;
      af[mf] = *(const short8*)&Ab[r * 32 + (kgrp ^ ((r >> 1) & 3)) * 8];
    }
#pragma unroll
    for (int nf = 0; nf < 4; ++nf) {
      int r = wn * 64 + nf * 16 + qlane;
      bf[nf] = *(const short8*)&Bb[r * 32 + (kgrp ^ ((r >> 1) & 3)) * 8];
    }
    __builtin_amdgcn_s_setprio(1);
#pragma unroll
    for (int mf = 0; mf < 4; ++mf)
#pragma unroll
      for (int nf = 0; nf < 4; ++nf)
        acc[mf][nf] = __builtin_amdgcn_mfma_f32_16x16x32_bf16(
            af[mf], bf[nf], acc[mf][nf], 0, 0, 0);
    __builtin_amdgcn_s_setprio(0);
  };

  stage(0); stage(1); stage(2);
  vmwait<6>();  // slab 0 landed (slabs 1,2 = 6 loads may stay outstanding)
  wgbar();
  for (int s = 0; s < NSLAB; ++s) {
    if (s + 3 < NSLAB) stage(s + 3);
    comp(s);
    if (s + 3 < NSLAB)      { vmwait<6>(); wgbar(); }   // slab s+1 landed
    else if (s + 2 < NSLAB) { vmwait<3>(); wgbar(); }
    else if (s + 1 < NSLAB) { vmwait<0>(); wgbar(); }
  }

  // epilogue
#pragma unroll
  for (int nf = 0; nf < 4; ++nf) {
    int col = bn * BN + wn * 64 + nf * 16 + qlane;
    float bv = bias[col];
#pragma unroll
    for (int mf = 0; mf < 4; ++mf) {
      int row0 = bm * BM + wm * 64 + mf * 16 + kgrp * 4;
#pragma unroll
      for (int r = 0; r < 4; ++r) {
        float v = acc[mf][nf][r] + bv;
        if (OUT_BF16)
          ((u16*)Cout)[(size_t)(row0 + r) * N + col] = f2bf(v);
        else
          ((float*)Cout)[(size_t)(row0 + r) * N + col] = v;
      }
    }
  }
}

// ---------------- banded local attention ----------------
__global__ __launch_bounds__(256, 2) void attn_local(
    const u16* __restrict__ qkv, const int* __restrict__ amask,
    u16* __restrict__ aout) {
  __shared__ __align__(16) u16 Kl[192][72];
  __shared__ __align__(16) u16 Vt[64][200];
  __shared__ __align__(16) u16 Pl[4][32][104];

  const int tid = threadIdx.x, wave = tid >> 6, lane = tid & 63;
  const int qlane = lane & 15, kgrp = lane >> 4;
  const int bz = blockIdx.x;
  const int qt = bz & 15, h = (bz >> 4) & 15, b = bz >> 8;
  const int qs0 = qt * 128;
  const int jt = qs0 - 32;
  const size_t rbase = (size_t)b * S_LEN;

  {
    const int r0 = tid >> 3, c0 = (tid & 7) * 8;
#pragma unroll
    for (int p = 0; p < 6; ++p) {
      int row = p * 32 + r0;
      int j = jt + row;
      u16 kv[8], vv[8];
      if (j >= 0 && j < S_LEN) {
        const u16* kp = qkv + (rbase + j) * QKV_LD + HID + h * 64 + c0;
        *(short8*)kv = *(const short8*)kp;
        *(short8*)vv = *(const short8*)(kp + HID);
      } else {
#pragma unroll
        for (int q = 0; q < 8; ++q) { kv[q] = 0; vv[q] = 0; }
      }
      *(short8*)&Kl[row][c0] = *(short8*)kv;
#pragma unroll
      for (int q = 0; q < 8; ++q) Vt[c0 + q][row] = vv[q];
    }
  }

  short8 qf[2][2];
#pragma unroll
  for (int mf = 0; mf < 2; ++mf)
#pragma unroll
    for (int kk = 0; kk < 2; ++kk)
      qf[mf][kk] = *(const short8*)(qkv +
          (rbase + qs0 + wave * 32 + mf * 16 + qlane) * QKV_LD +
          h * 64 + kk * 32 + kgrp * 8);

  __syncthreads();

  f32x4 sc[2][6] = {};
#pragma unroll
  for (int kk = 0; kk < 2; ++kk) {
    short8 kf[6];
#pragma unroll
    for (int nf = 0; nf < 6; ++nf)
      kf[nf] = *(const short8*)&Kl[wave * 32 + nf * 16 + qlane][kk * 32 + kgrp * 8];
#pragma unroll
    for (int mf = 0; mf < 2; ++mf)
#pragma unroll
      for (int nf = 0; nf < 6; ++nf)
        sc[mf][nf] = __builtin_amdgcn_mfma_f32_16x16x32_bf16(
            qf[mf][kk], kf[nf], sc[mf][nf], 0, 0, 0);
  }

  int jcol[6], mv[6];
#pragma unroll
  for (int nf = 0; nf < 6; ++nf) {
    int j = jt + wave * 32 + nf * 16 + qlane;
    jcol[nf] = j;
    mv[nf] = (j >= 0 && j < S_LEN) ? amask[rbase + j] : 0;
  }

  float inv[2][4];
#pragma unroll
  for (int mf = 0; mf < 2; ++mf) {
    const int irow0 = qs0 + wave * 32 + mf * 16 + kgrp * 4;
    float mx[4] = {-1e30f, -1e30f, -1e30f, -1e30f};
#pragma unroll
    for (int r = 0; r < 4; ++r) {
      int i = irow0 + r;
#pragma unroll
      for (int nf = 0; nf < 6; ++nf) {
        int d = i - jcol[nf];
        if (mv[nf] && d >= -32 && d <= 32) mx[r] = fmaxf(mx[r], sc[mf][nf][r]);
      }
    }
#pragma unroll
    for (int m = 1; m < 16; m <<= 1)
#pragma unroll
      for (int r = 0; r < 4; ++r)
        mx[r] = fmaxf(mx[r], __shfl_xor(mx[r], m));
    float sm[4] = {0.f, 0.f, 0.f, 0.f};
#pragma unroll
    for (int r = 0; r < 4; ++r) {
      int i = irow0 + r;
#pragma unroll
      for (int nf = 0; nf < 6; ++nf) {
        int d = i - jcol[nf];
        bool val = mv[nf] && d >= -32 && d <= 32;
        float p = val ? __expf((sc[mf][nf][r] - mx[r]) * 0.125f) : 0.f;
        sc[mf][nf][r] = p;
        sm[r] += p;
      }
    }
#pragma unroll
    for (int m = 1; m < 16; m <<= 1)
#pragma unroll
      for (int r = 0; r < 4; ++r)
        sm[r] += __shfl_xor(sm[r], m);
#pragma unroll
    for (int r = 0; r < 4; ++r)
      inv[mf][r] = sm[r] > 0.f ? 1.f / sm[r] : 0.f;
#pragma unroll
    for (int nf = 0; nf < 6; ++nf)
#pragma unroll
      for (int r = 0; r < 4; ++r)
        Pl[wave][mf * 16 + kgrp * 4 + r][nf * 16 + qlane] = f2bf(sc[mf][nf][r]);
  }
  __syncthreads();

  f32x4 oc[2][4] = {};
#pragma unroll
  for (int ks = 0; ks < 3; ++ks) {
    short8 pa[2], vb[4];
#pragma unroll
    for (int mf = 0; mf < 2; ++mf)
      pa[mf] = *(const short8*)&Pl[wave][mf * 16 + qlane][ks * 32 + kgrp * 8];
#pragma unroll
    for (int nf = 0; nf < 4; ++nf)
      vb[nf] = *(const short8*)&Vt[nf * 16 + qlane][wave * 32 + ks * 32 + kgrp * 8];
#pragma unroll
    for (int mf = 0; mf < 2; ++mf)
#pragma unroll
      for (int nf = 0; nf < 4; ++nf)
        oc[mf][nf] = __builtin_amdgcn_mfma_f32_16x16x32_bf16(
            pa[mf], vb[nf], oc[mf][nf], 0, 0, 0);
  }

#pragma unroll
  for (int mf = 0; mf < 2; ++mf)
#pragma unroll
    for (int nf = 0; nf < 4; ++nf)
#pragma unroll
      for (int r = 0; r < 4; ++r) {
        size_t row = rbase + qs0 + wave * 32 + mf * 16 + kgrp * 4 + r;
        aout[row * HID + h * 64 + nf * 16 + qlane] =
            f2bf(oc[mf][nf][r] * inv[mf][r]);
      }
}

// ---------------- launch ----------------
extern "C" void kernel_launch(void* const* d_in, const int* in_sizes, int n_in,
                              void* d_out, int out_size, void* d_ws, size_t ws_size,
                              hipStream_t stream) {
  const float* x  = (const float*)d_in[0];
  const int* amask = (const int*)d_in[1];
  const float* Wq = (const float*)d_in[2];
  const float* bq = (const float*)d_in[3];
  const float* Wk = (const float*)d_in[4];
  const float* bk = (const float*)d_in[5];
  const float* Wv = (const float*)d_in[6];
  const float* bv = (const float*)d_in[7];
  const float* Wo = (const float*)d_in[8];
  const float* bo = (const float*)d_in[9];
  float* out = (float*)d_out;

  char* w = (char*)d_ws;
  u16* xb    = (u16*)w;   w += (size_t)M_ROWS * HID * 2;
  u16* wqkvt = (u16*)w;   w += (size_t)3072 * 1024 * 2;
  u16* wot   = (u16*)w;   w += (size_t)1024 * 1024 * 2;
  float* bqkv = (float*)w; w += 3072 * 4 + 256;
  u16* qkv   = (u16*)w;   w += (size_t)M_ROWS * 3072 * 2;
  u16* aout  = (u16*)w;   w += (size_t)M_ROWS * HID * 2;

  cvt_f32_to_bf16<<<4096, 256, 0, stream>>>(x, xb, M_ROWS * HID);
  dim3 tg(32, 32);
  transpose_to_bf16<<<tg, 256, 0, stream>>>(Wq, wqkvt,                1024, 1024);
  transpose_to_bf16<<<tg, 256, 0, stream>>>(Wk, wqkvt + 1024 * 1024,  1024, 1024);
  transpose_to_bf16<<<tg, 256, 0, stream>>>(Wv, wqkvt + 2048 * 1024,  1024, 1024);
  transpose_to_bf16<<<tg, 256, 0, stream>>>(Wo, wot,                  1024, 1024);
  pack_bias<<<12, 256, 0, stream>>>(bq, bk, bv, bqkv);

  gemm_p<1><<<768, 512, 0, stream>>>(xb, wqkvt, bqkv, qkv, M_ROWS, 3072);
  attn_local<<<1024, 256, 0, stream>>>(qkv, amask, aout);
  gemm_p<0><<<256, 512, 0, stream>>>(aout, wot, bo, out, M_ROWS, 1024);
}

// Round 3
// 132.254 us; speedup vs baseline: 1.0812x; 1.0812x over previous
//
#include <hip/hip_runtime.h>
#include <stdint.h>

typedef unsigned short u16;
typedef __attribute__((ext_vector_type(8))) short short8;
typedef __attribute__((ext_vector_type(4))) float f32x4;

#define S_LEN 2048
#define HID   1024
#define QKV_LD 3072
#define M_ROWS 8192   // B*S

__device__ __forceinline__ u16 f2bf(float f) {
  unsigned u = __float_as_uint(f);
  unsigned r = (u + 0x7fffu + ((u >> 16) & 1u)) >> 16;
  return (u16)r;
}

__device__ __forceinline__ void gload16(const u16* g, u16* l) {
  __builtin_amdgcn_global_load_lds(
      (const __attribute__((address_space(1))) unsigned int*)(g),
      (__attribute__((address_space(3))) unsigned int*)(l),
      16, 0, 0);
}

__device__ __forceinline__ void wgbar() {
  asm volatile("" ::: "memory");
  __builtin_amdgcn_s_barrier();
  asm volatile("" ::: "memory");
}

// ---------------- fused cvt(x)->bf16 + bias pack ----------------
__global__ __launch_bounds__(256) void cvt_bias(
    const float* __restrict__ in, u16* __restrict__ out, int n,
    const float* __restrict__ bq, const float* __restrict__ bk,
    const float* __restrict__ bv, float* __restrict__ bqkv) {
  if (blockIdx.x == (unsigned)(n / (256 * 8))) {
    for (int i = threadIdx.x; i < 3072; i += 256)
      bqkv[i] = (i < 1024) ? bq[i] : (i < 2048) ? bk[i - 1024] : bv[i - 2048];
    return;
  }
  int i = (blockIdx.x * 256 + threadIdx.x) * 8;
  float4 a = *(const float4*)(in + i);
  float4 b = *(const float4*)(in + i + 4);
  u16 t[8];
  t[0] = f2bf(a.x); t[1] = f2bf(a.y); t[2] = f2bf(a.z); t[3] = f2bf(a.w);
  t[4] = f2bf(b.x); t[5] = f2bf(b.y); t[6] = f2bf(b.z); t[7] = f2bf(b.w);
  *(short8*)(out + i) = *(short8*)t;
}

// all 4 weight transposes in one launch: f32 [1024][1024] -> bf16 [N][K] (B^T)
__global__ __launch_bounds__(256) void pack_weights(
    const float* __restrict__ Wq, const float* __restrict__ Wk,
    const float* __restrict__ Wv, const float* __restrict__ Wo,
    u16* __restrict__ wqkvt, u16* __restrict__ wot) {
  __shared__ float tile[32][33];
  const int z = blockIdx.z;
  const float* in = (z == 0) ? Wq : (z == 1) ? Wk : (z == 2) ? Wv : Wo;
  u16* out = (z < 3) ? (wqkvt + (size_t)z * 1024 * 1024) : wot;
  int tx = threadIdx.x & 31, ty = threadIdx.x >> 5;
  int n0 = blockIdx.x * 32, k0 = blockIdx.y * 32;
#pragma unroll
  for (int i = 0; i < 32; i += 8)
    tile[ty + i][tx] = in[(size_t)(k0 + ty + i) * 1024 + n0 + tx];
  __syncthreads();
#pragma unroll
  for (int i = 0; i < 32; i += 8)
    out[(size_t)(n0 + ty + i) * 1024 + k0 + tx] = f2bf(tile[tx][ty + i]);
}

// ---------------- 8-phase pipelined GEMM ----------------
// C[M,N] = A[M,1024] * Bt[N,1024]^T + bias.  BM=256 x BN=128, BK=64,
// 8 waves (4M x 2N), per-wave C = 64x64 (4x4 frags).  Ring-3 LDS buffers
// (48 KiB each, 144 KiB total).  Per K-tile: 2 phases x 16 MFMA; each phase
// issues 3 global_load_lds for tile t+2 into b[(t+2)%3] (holds tile t-1,
// readers done one barrier ago -> no aliasing).  vmcnt(6) once per tile
// boundary: the 6 newest loads are tile t+2's, so all of tile t+1 landed.
// XOR slot swizzle (slot ^= row&7) on staged source + frag reads: uniform
// bank distribution (measured 0 conflicts in round 1).
template<int OUT_BF16>
__global__ __launch_bounds__(512, 2) void gemm_p(
    const u16* __restrict__ A, const u16* __restrict__ Bt,
    const float* __restrict__ bias, void* __restrict__ Cout,
    int M, int N) {
  constexpr int K = 1024, NT = 16;          // K-tiles of 64
  constexpr int BM = 256, BN = 128;
  constexpr int AU = BM * 64;               // 16384 u16 per A tile
  constexpr int BUF = (BM + BN) * 64;       // 24576 u16 per ring slot
  __shared__ __align__(16) u16 smem[3 * BUF];   // 144 KiB

  const int tid = threadIdx.x;
  const int wave = tid >> 6, lane = tid & 63;
  const int qlane = lane & 15, kgrp = lane >> 4;
  const int wm = wave >> 1, wn = wave & 1;
  const int nbn = N >> 7;
  int wg = blockIdx.x;
  const int cpx = (int)gridDim.x >> 3;      // grid % 8 == 0 by construction
  wg = (wg & 7) * cpx + (wg >> 3);
  const int bm = wg / nbn, bn = wg % nbn;

  // staging: 6 units/tile of 1 gload16/thread (512 thr x 16B = 64 rows).
  // unit u<4: A rows u*64.. ; u>=4: B rows (u-4)*64..
  const int srow = tid >> 3;                        // 0..63 within unit
  const int sslot = (tid & 7) ^ (srow & 7);         // inverse-swizzled source
  size_t goff[6];
  int loff[6];
#pragma unroll
  for (int u = 0; u < 4; ++u) {
    goff[u] = (size_t)(bm * BM + u * 64 + srow) * K + sslot * 8;
    loff[u] = u * 4096 + tid * 8;
  }
#pragma unroll
  for (int u = 0; u < 2; ++u) {
    goff[4 + u] = (size_t)(bn * BN + u * 64 + srow) * K + sslot * 8;
    loff[4 + u] = AU + u * 4096 + tid * 8;
  }

  auto stage = [&](int t, int u) {
    const u16* g = (u < 4 ? A : Bt) + goff[u] + t * 64;
    gload16(g, &smem[(t % 3) * BUF + loff[u]]);
  };

  f32x4 acc[4][4] = {};

  // prologue: tiles 0,1
#pragma unroll
  for (int u = 0; u < 6; ++u) stage(0, u);
#pragma unroll
  for (int u = 0; u < 6; ++u) stage(1, u);
  asm volatile("s_waitcnt vmcnt(6)" ::: "memory");   // tile 0 landed
  wgbar();

  for (int t = 0; t < NT; ++t) {
    const u16* bp = &smem[(t % 3) * BUF];
    const bool st = (t + 2 < NT);
    short8 bfr[4][2], afr[2][2];

    // ---- phase 0: read A mf0,1 + all B; stage units 0-2 of t+2 ----
#pragma unroll
    for (int mf = 0; mf < 2; ++mf)
#pragma unroll
      for (int kk = 0; kk < 2; ++kk) {
        int r = wm * 64 + mf * 16 + qlane;
        afr[mf][kk] = *(const short8*)&bp[r * 64 + ((kk * 4 + kgrp) ^ (r & 7)) * 8];
      }
#pragma unroll
    for (int nf = 0; nf < 4; ++nf)
#pragma unroll
      for (int kk = 0; kk < 2; ++kk) {
        int r = wn * 64 + nf * 16 + qlane;
        bfr[nf][kk] = *(const short8*)&bp[AU + r * 64 + ((kk * 4 + kgrp) ^ (r & 7)) * 8];
      }
    if (st) { stage(t + 2, 0); stage(t + 2, 1); stage(t + 2, 2); }
    wgbar();
    asm volatile("s_waitcnt lgkmcnt(0)" ::: "memory");
    __builtin_amdgcn_s_setprio(1);
#pragma unroll
    for (int mf = 0; mf < 2; ++mf)
#pragma unroll
      for (int nf = 0; nf < 4; ++nf)
#pragma unroll
        for (int kk = 0; kk < 2; ++kk)
          acc[mf][nf] = __builtin_amdgcn_mfma_f32_16x16x32_bf16(
              afr[mf][kk], bfr[nf][kk], acc[mf][nf], 0, 0, 0);
    __builtin_amdgcn_s_setprio(0);
    wgbar();

    // ---- phase 1: read A mf2,3; stage units 3-5 of t+2 ----
#pragma unroll
    for (int mf = 0; mf < 2; ++mf)
#pragma unroll
      for (int kk = 0; kk < 2; ++kk) {
        int r = wm * 64 + (mf + 2) * 16 + qlane;
        afr[mf][kk] = *(const short8*)&bp[r * 64 + ((kk * 4 + kgrp) ^ (r & 7)) * 8];
      }
    if (st) { stage(t + 2, 3); stage(t + 2, 4); stage(t + 2, 5); }
    wgbar();
    asm volatile("s_waitcnt lgkmcnt(0)" ::: "memory");
    __builtin_amdgcn_s_setprio(1);
#pragma unroll
    for (int mf = 0; mf < 2; ++mf)
#pragma unroll
      for (int nf = 0; nf < 4; ++nf)
#pragma unroll
        for (int kk = 0; kk < 2; ++kk)
          acc[mf + 2][nf] = __builtin_amdgcn_mfma_f32_16x16x32_bf16(
              afr[mf][kk], bfr[nf][kk], acc[mf + 2][nf], 0, 0, 0);
    __builtin_amdgcn_s_setprio(0);
    if (st)                asm volatile("s_waitcnt vmcnt(6)" ::: "memory");
    else if (t + 1 < NT)   asm volatile("s_waitcnt vmcnt(0)" ::: "memory");
    if (t + 1 < NT) wgbar();
  }

  // epilogue
#pragma unroll
  for (int nf = 0; nf < 4; ++nf) {
    int col = bn * BN + wn * 64 + nf * 16 + qlane;
    float bv = bias[col];
#pragma unroll
    for (int mf = 0; mf < 4; ++mf) {
      int row0 = bm * BM + wm * 64 + mf * 16 + kgrp * 4;
#pragma unroll
      for (int r = 0; r < 4; ++r) {
        float v = acc[mf][nf][r] + bv;
        if (OUT_BF16)
          ((u16*)Cout)[(size_t)(row0 + r) * N + col] = f2bf(v);
        else
          ((float*)Cout)[(size_t)(row0 + r) * N + col] = v;
      }
    }
  }
}

// ---------------- banded local attention (unchanged, proven) ----------------
__global__ __launch_bounds__(256, 2) void attn_local(
    const u16* __restrict__ qkv, const int* __restrict__ amask,
    u16* __restrict__ aout) {
  __shared__ __align__(16) u16 Kl[192][72];
  __shared__ __align__(16) u16 Vt[64][200];
  __shared__ __align__(16) u16 Pl[4][32][104];

  const int tid = threadIdx.x, wave = tid >> 6, lane = tid & 63;
  const int qlane = lane & 15, kgrp = lane >> 4;
  const int bz = blockIdx.x;
  const int qt = bz & 15, h = (bz >> 4) & 15, b = bz >> 8;
  const int qs0 = qt * 128;
  const int jt = qs0 - 32;
  const size_t rbase = (size_t)b * S_LEN;

  {
    const int r0 = tid >> 3, c0 = (tid & 7) * 8;
#pragma unroll
    for (int p = 0; p < 6; ++p) {
      int row = p * 32 + r0;
      int j = jt + row;
      u16 kv[8], vv[8];
      if (j >= 0 && j < S_LEN) {
        const u16* kp = qkv + (rbase + j) * QKV_LD + HID + h * 64 + c0;
        *(short8*)kv = *(const short8*)kp;
        *(short8*)vv = *(const short8*)(kp + HID);
      } else {
#pragma unroll
        for (int q = 0; q < 8; ++q) { kv[q] = 0; vv[q] = 0; }
      }
      *(short8*)&Kl[row][c0] = *(short8*)kv;
#pragma unroll
      for (int q = 0; q < 8; ++q) Vt[c0 + q][row] = vv[q];
    }
  }

  short8 qf[2][2];
#pragma unroll
  for (int mf = 0; mf < 2; ++mf)
#pragma unroll
    for (int kk = 0; kk < 2; ++kk)
      qf[mf][kk] = *(const short8*)(qkv +
          (rbase + qs0 + wave * 32 + mf * 16 + qlane) * QKV_LD +
          h * 64 + kk * 32 + kgrp * 8);

  __syncthreads();

  f32x4 sc[2][6] = {};
#pragma unroll
  for (int kk = 0; kk < 2; ++kk) {
    short8 kf[6];
#pragma unroll
    for (int nf = 0; nf < 6; ++nf)
      kf[nf] = *(const short8*)&Kl[wave * 32 + nf * 16 + qlane][kk * 32 + kgrp * 8];
#pragma unroll
    for (int mf = 0; mf < 2; ++mf)
#pragma unroll
      for (int nf = 0; nf < 6; ++nf)
        sc[mf][nf] = __builtin_amdgcn_mfma_f32_16x16x32_bf16(
            qf[mf][kk], kf[nf], sc[mf][nf], 0, 0, 0);
  }

  int jcol[6], mv[6];
#pragma unroll
  for (int nf = 0; nf < 6; ++nf) {
    int j = jt + wave * 32 + nf * 16 + qlane;
    jcol[nf] = j;
    mv[nf] = (j >= 0 && j < S_LEN) ? amask[rbase + j] : 0;
  }

  float inv[2][4];
#pragma unroll
  for (int mf = 0; mf < 2; ++mf) {
    const int irow0 = qs0 + wave * 32 + mf * 16 + kgrp * 4;
    float mx[4] = {-1e30f, -1e30f, -1e30f, -1e30f};
#pragma unroll
    for (int r = 0; r < 4; ++r) {
      int i = irow0 + r;
#pragma unroll
      for (int nf = 0; nf < 6; ++nf) {
        int d = i - jcol[nf];
        if (mv[nf] && d >= -32 && d <= 32) mx[r] = fmaxf(mx[r], sc[mf][nf][r]);
      }
    }
#pragma unroll
    for (int m = 1; m < 16; m <<= 1)
#pragma unroll
      for (int r = 0; r < 4; ++r)
        mx[r] = fmaxf(mx[r], __shfl_xor(mx[r], m));
    float sm[4] = {0.f, 0.f, 0.f, 0.f};
#pragma unroll
    for (int r = 0; r < 4; ++r) {
      int i = irow0 + r;
#pragma unroll
      for (int nf = 0; nf < 6; ++nf) {
        int d = i - jcol[nf];
        bool val = mv[nf] && d >= -32 && d <= 32;
        float p = val ? __expf((sc[mf][nf][r] - mx[r]) * 0.125f) : 0.f;
        sc[mf][nf][r] = p;
        sm[r] += p;
      }
    }
#pragma unroll
    for (int m = 1; m < 16; m <<= 1)
#pragma unroll
      for (int r = 0; r < 4; ++r)
        sm[r] += __shfl_xor(sm[r], m);
#pragma unroll
    for (int r = 0; r < 4; ++r)
      inv[mf][r] = sm[r] > 0.f ? 1.f / sm[r] : 0.f;
#pragma unroll
    for (int nf = 0; nf < 6; ++nf)
#pragma unroll
      for (int r = 0; r < 4; ++r)
        Pl[wave][mf * 16 + kgrp * 4 + r][nf * 16 + qlane] = f2bf(sc[mf][nf][r]);
  }
  __syncthreads();

  f32x4 oc[2][4] = {};
#pragma unroll
  for (int ks = 0; ks < 3; ++ks) {
    short8 pa[2], vb[4];
#pragma unroll
    for (int mf = 0; mf < 2; ++mf)
      pa[mf] = *(const short8*)&Pl[wave][mf * 16 + qlane][ks * 32 + kgrp * 8];
#pragma unroll
    for (int nf = 0; nf < 4; ++nf)
      vb[nf] = *(const short8*)&Vt[nf * 16 + qlane][wave * 32 + ks * 32 + kgrp * 8];
#pragma unroll
    for (int mf = 0; mf < 2; ++mf)
#pragma unroll
      for (int nf = 0; nf < 4; ++nf)
        oc[mf][nf] = __builtin_amdgcn_mfma_f32_16x16x32_bf16(
            pa[mf], vb[nf], oc[mf][nf], 0, 0, 0);
  }

#pragma unroll
  for (int mf = 0; mf < 2; ++mf)
#pragma unroll
    for (int nf = 0; nf < 4; ++nf)
#pragma unroll
      for (int r = 0; r < 4; ++r) {
        size_t row = rbase + qs0 + wave * 32 + mf * 16 + kgrp * 4 + r;
        aout[row * HID + h * 64 + nf * 16 + qlane] =
            f2bf(oc[mf][nf][r] * inv[mf][r]);
      }
}

// ---------------- launch ----------------
extern "C" void kernel_launch(void* const* d_in, const int* in_sizes, int n_in,
                              void* d_out, int out_size, void* d_ws, size_t ws_size,
                              hipStream_t stream) {
  const float* x  = (const float*)d_in[0];
  const int* amask = (const int*)d_in[1];
  const float* Wq = (const float*)d_in[2];
  const float* bq = (const float*)d_in[3];
  const float* Wk = (const float*)d_in[4];
  const float* bk = (const float*)d_in[5];
  const float* Wv = (const float*)d_in[6];
  const float* bv = (const float*)d_in[7];
  const float* Wo = (const float*)d_in[8];
  const float* bo = (const float*)d_in[9];
  float* out = (float*)d_out;

  char* w = (char*)d_ws;
  u16* xb    = (u16*)w;   w += (size_t)M_ROWS * HID * 2;
  u16* wqkvt = (u16*)w;   w += (size_t)3072 * 1024 * 2;
  u16* wot   = (u16*)w;   w += (size_t)1024 * 1024 * 2;
  float* bqkv = (float*)w; w += 3072 * 4 + 256;
  u16* qkv   = (u16*)w;   w += (size_t)M_ROWS * 3072 * 2;
  u16* aout  = (u16*)w;   w += (size_t)M_ROWS * HID * 2;

  cvt_bias<<<4097, 256, 0, stream>>>(x, xb, M_ROWS * HID, bq, bk, bv, bqkv);
  pack_weights<<<dim3(32, 32, 4), 256, 0, stream>>>(Wq, Wk, Wv, Wo, wqkvt, wot);

  gemm_p<1><<<768, 512, 0, stream>>>(xb, wqkvt, bqkv, qkv, M_ROWS, 3072);
  attn_local<<<1024, 256, 0, stream>>>(qkv, amask, aout);
  gemm_p<0><<<256, 512, 0, stream>>>(aout, wot, bo, out, M_ROWS, 1024);
}

// Round 4
// 120.839 us; speedup vs baseline: 1.1834x; 1.0945x over previous
//
#include <hip/hip_runtime.h>
#include <stdint.h>

typedef unsigned short u16;
typedef __attribute__((ext_vector_type(8))) short short8;
typedef __attribute__((ext_vector_type(4))) float f32x4;

#define S_LEN 2048
#define HID   1024
#define QKV_LD 3072
#define M_ROWS 8192   // B*S

__device__ __forceinline__ u16 f2bf(float f) {
  unsigned u = __float_as_uint(f);
  unsigned r = (u + 0x7fffu + ((u >> 16) & 1u)) >> 16;
  return (u16)r;
}

__device__ __forceinline__ void gload16(const u16* g, u16* l) {
  __builtin_amdgcn_global_load_lds(
      (const __attribute__((address_space(1))) unsigned int*)(g),
      (__attribute__((address_space(3))) unsigned int*)(l),
      16, 0, 0);
}

__device__ __forceinline__ void wgbar() {
  asm volatile("" ::: "memory");
  __builtin_amdgcn_s_barrier();
  asm volatile("" ::: "memory");
}

// ---------------- fused cvt(x)->bf16 + bias pack ----------------
__global__ __launch_bounds__(256) void cvt_bias(
    const float* __restrict__ in, u16* __restrict__ out, int n,
    const float* __restrict__ bq, const float* __restrict__ bk,
    const float* __restrict__ bv, float* __restrict__ bqkv) {
  if (blockIdx.x == (unsigned)(n / (256 * 8))) {
    for (int i = threadIdx.x; i < 3072; i += 256)
      bqkv[i] = (i < 1024) ? bq[i] : (i < 2048) ? bk[i - 1024] : bv[i - 2048];
    return;
  }
  int i = (blockIdx.x * 256 + threadIdx.x) * 8;
  float4 a = *(const float4*)(in + i);
  float4 b = *(const float4*)(in + i + 4);
  u16 t[8];
  t[0] = f2bf(a.x); t[1] = f2bf(a.y); t[2] = f2bf(a.z); t[3] = f2bf(a.w);
  t[4] = f2bf(b.x); t[5] = f2bf(b.y); t[6] = f2bf(b.z); t[7] = f2bf(b.w);
  *(short8*)(out + i) = *(short8*)t;
}

// all 4 weight transposes in one launch: f32 [1024][1024] -> bf16 [N][K] (B^T)
__global__ __launch_bounds__(256) void pack_weights(
    const float* __restrict__ Wq, const float* __restrict__ Wk,
    const float* __restrict__ Wv, const float* __restrict__ Wo,
    u16* __restrict__ wqkvt, u16* __restrict__ wot) {
  __shared__ float tile[32][33];
  const int z = blockIdx.z;
  const float* in = (z == 0) ? Wq : (z == 1) ? Wk : (z == 2) ? Wv : Wo;
  u16* out = (z < 3) ? (wqkvt + (size_t)z * 1024 * 1024) : wot;
  int tx = threadIdx.x & 31, ty = threadIdx.x >> 5;
  int n0 = blockIdx.x * 32, k0 = blockIdx.y * 32;
#pragma unroll
  for (int i = 0; i < 32; i += 8)
    tile[ty + i][tx] = in[(size_t)(k0 + ty + i) * 1024 + n0 + tx];
  __syncthreads();
#pragma unroll
  for (int i = 0; i < 32; i += 8)
    out[(size_t)(n0 + ty + i) * 1024 + k0 + tx] = f2bf(tile[tx][ty + i]);
}

// ---------------- GEMM1: ring-2 counted-vmcnt pipeline ----------------
// C[M,3072] = A[M,1024] * Bt[3072,1024]^T + bias, bf16 out.
// BM=128 x BN=192, BK=64, 4 waves (2M x 2N), per-wave 64x96 (4x6 frags).
// LDS = 2 buffers x 40 KiB = 80 KiB -> exactly 2 blocks/CU (independent
// blocks hide each other's stalls).  Grid 64x16=1024 = 2.0 clean rounds.
// Per K-tile: 3 phases x 16 MFMA, reads 12/4/4 (A frags held all phases).
// Chunk-safe staging (chunk = 64 rows; last-read phases: A:P1, B-c0:P2,
// B-c1:P3, B-c2:P3):
//   P1: stage B-c1,c2(t+1) -> other buffer (occupant t-1 done)      [4 ld]
//   P2: stage A(t+2)       -> same buffer, A last read P1 + barrier [4 ld]
//   P3: stage B-c0(t+2)    -> same buffer, c0 last read P2 + barrier[2 ld]
// Gate: one vmcnt(6) per tile at P3-end = exactly the 6 loads newer than
// tile t+1's last piece (B-c2(t+1) issued at P1) -> t+1 fully landed.
// XOR slot swizzle (slot ^= row&7) on pre-swizzled source + frag reads:
// 2 lanes/bank on ds_read_b128 (0 conflicts measured rounds 1-3).
__global__ __launch_bounds__(256, 2) void gemm_k1(
    const u16* __restrict__ A, const u16* __restrict__ Bt,
    const float* __restrict__ bias, u16* __restrict__ C, int N) {
  constexpr int K = 1024, NT = 16;
  constexpr int BM = 128, BN = 192;
  constexpr int AU = BM * 64;               // 8192 u16
  constexpr int BUF = (BM + BN) * 64;       // 20480 u16 (40 KiB)
  __shared__ __align__(16) u16 smem[2 * BUF];   // 80 KiB

  const int tid = threadIdx.x;
  const int wave = tid >> 6, lane = tid & 63;
  const int qlane = lane & 15, kgrp = lane >> 4;
  const int wm = wave >> 1, wn = wave & 1;
  const int nbn = N / BN;                   // 16
  int wg = blockIdx.x;
  const int cpx = (int)gridDim.x >> 3;      // 1024 % 8 == 0
  wg = (wg & 7) * cpx + (wg >> 3);
  const int bm = wg / nbn, bn = wg % nbn;

  // staging: unit = 32 rows x 64 cols (4 KiB = 256 thr x 16 B)
  const int srow = tid >> 3;                // 0..31
  const int sslot = tid & 7;
  uint32_t gA[4], gB[6];
#pragma unroll
  for (int au = 0; au < 4; ++au) {
    int row = au * 32 + srow;
    gA[au] = (uint32_t)((bm * BM + row) * K + ((sslot ^ (row & 7)) * 8));
  }
#pragma unroll
  for (int bu = 0; bu < 6; ++bu) {
    int row = bu * 32 + srow;
    gB[bu] = (uint32_t)((bn * BN + row) * K + ((sslot ^ (row & 7)) * 8));
  }

  auto stgA = [&](int t, int au) {
    gload16(A + (size_t)gA[au] + t * 64, &smem[(t & 1) * BUF + au * 2048 + tid * 8]);
  };
  auto stgB = [&](int t, int bu) {
    gload16(Bt + (size_t)gB[bu] + t * 64, &smem[(t & 1) * BUF + AU + bu * 2048 + tid * 8]);
  };

  // prologue: tile0 (10 units), A(1) (4), B-c0(1) (2) = 16 loads
#pragma unroll
  for (int au = 0; au < 4; ++au) stgA(0, au);
#pragma unroll
  for (int bu = 0; bu < 6; ++bu) stgB(0, bu);
#pragma unroll
  for (int au = 0; au < 4; ++au) stgA(1, au);
  stgB(1, 0); stgB(1, 1);
  asm volatile("s_waitcnt vmcnt(6)" ::: "memory");   // tile 0 landed
  wgbar();

  f32x4 acc[4][6] = {};
  short8 af[4][2], bf[2][2];

  for (int t = 0; t < NT; ++t) {
    const u16* bp = &smem[(t & 1) * BUF];

    // ---- P1: read A (8) + B nf0-1 (4); stage B-c1,c2(t+1) ----
#pragma unroll
    for (int mf = 0; mf < 4; ++mf)
#pragma unroll
      for (int kk = 0; kk < 2; ++kk) {
        int r = wm * 64 + mf * 16 + qlane;
        af[mf][kk] = *(const short8*)&bp[r * 64 + ((kk * 4 + kgrp) ^ (r & 7)) * 8];
      }
#pragma unroll
    for (int nf = 0; nf < 2; ++nf)
#pragma unroll
      for (int kk = 0; kk < 2; ++kk) {
        int r = wn * 96 + nf * 16 + qlane;
        bf[nf][kk] = *(const short8*)&bp[AU + r * 64 + ((kk * 4 + kgrp) ^ (r & 7)) * 8];
      }
    if (t + 1 < NT) { stgB(t + 1, 2); stgB(t + 1, 3); stgB(t + 1, 4); stgB(t + 1, 5); }
    wgbar();
    asm volatile("s_waitcnt lgkmcnt(0)" ::: "memory");
    __builtin_amdgcn_s_setprio(1);
#pragma unroll
    for (int mf = 0; mf < 4; ++mf)
#pragma unroll
      for (int nf = 0; nf < 2; ++nf)
#pragma unroll
        for (int kk = 0; kk < 2; ++kk)
          acc[mf][nf] = __builtin_amdgcn_mfma_f32_16x16x32_bf16(
              af[mf][kk], bf[nf][kk], acc[mf][nf], 0, 0, 0);
    __builtin_amdgcn_s_setprio(0);
    wgbar();

    // ---- P2: read B nf2-3 (4); stage A(t+2) ----
#pragma unroll
    for (int nf = 0; nf < 2; ++nf)
#pragma unroll
      for (int kk = 0; kk < 2; ++kk) {
        int r = wn * 96 + (nf + 2) * 16 + qlane;
        bf[nf][kk] = *(const short8*)&bp[AU + r * 64 + ((kk * 4 + kgrp) ^ (r & 7)) * 8];
      }
    if (t + 2 < NT) { stgA(t + 2, 0); stgA(t + 2, 1); stgA(t + 2, 2); stgA(t + 2, 3); }
    wgbar();
    asm volatile("s_waitcnt lgkmcnt(0)" ::: "memory");
    __builtin_amdgcn_s_setprio(1);
#pragma unroll
    for (int mf = 0; mf < 4; ++mf)
#pragma unroll
      for (int nf = 0; nf < 2; ++nf)
#pragma unroll
        for (int kk = 0; kk < 2; ++kk)
          acc[mf][nf + 2] = __builtin_amdgcn_mfma_f32_16x16x32_bf16(
              af[mf][kk], bf[nf][kk], acc[mf][nf + 2], 0, 0, 0);
    __builtin_amdgcn_s_setprio(0);
    wgbar();

    // ---- P3: read B nf4-5 (4); stage B-c0(t+2); gate vmcnt ----
#pragma unroll
    for (int nf = 0; nf < 2; ++nf)
#pragma unroll
      for (int kk = 0; kk < 2; ++kk) {
        int r = wn * 96 + (nf + 4) * 16 + qlane;
        bf[nf][kk] = *(const short8*)&bp[AU + r * 64 + ((kk * 4 + kgrp) ^ (r & 7)) * 8];
      }
    if (t + 2 < NT) { stgB(t + 2, 0); stgB(t + 2, 1); }
    wgbar();
    asm volatile("s_waitcnt lgkmcnt(0)" ::: "memory");
    __builtin_amdgcn_s_setprio(1);
#pragma unroll
    for (int mf = 0; mf < 4; ++mf)
#pragma unroll
      for (int nf = 0; nf < 2; ++nf)
#pragma unroll
        for (int kk = 0; kk < 2; ++kk)
          acc[mf][nf + 4] = __builtin_amdgcn_mfma_f32_16x16x32_bf16(
              af[mf][kk], bf[nf][kk], acc[mf][nf + 4], 0, 0, 0);
    __builtin_amdgcn_s_setprio(0);
    if (t + 2 < NT)      asm volatile("s_waitcnt vmcnt(6)" ::: "memory");
    else if (t + 1 < NT) asm volatile("s_waitcnt vmcnt(0)" ::: "memory");
    if (t + 1 < NT) wgbar();
  }

  // epilogue
#pragma unroll
  for (int nf = 0; nf < 6; ++nf) {
    int col = bn * BN + wn * 96 + nf * 16 + qlane;
    float bv = bias[col];
#pragma unroll
    for (int mf = 0; mf < 4; ++mf) {
      int row0 = bm * BM + wm * 64 + mf * 16 + kgrp * 4;
#pragma unroll
      for (int r = 0; r < 4; ++r)
        C[(size_t)(row0 + r) * N + col] = f2bf(acc[mf][nf][r] + bv);
    }
  }
}

// ---------------- GEMM (round-1 structure, for output projection) --------
template<int OUT_BF16>
__global__ __launch_bounds__(256, 2) void gemm_bt(
    const u16* __restrict__ A, const u16* __restrict__ Bt,
    const float* __restrict__ bias, void* __restrict__ Cout,
    int M, int N, int K) {
  __shared__ __align__(16) u16 Al[128 * 64];
  __shared__ __align__(16) u16 Bl[128 * 64];
  const int tid = threadIdx.x;
  const int wave = tid >> 6, lane = tid & 63;
  const int nbn = N >> 7;
  int wg = blockIdx.x;
  const int cpx = (int)gridDim.x >> 3;
  wg = (wg & 7) * cpx + (wg >> 3);
  const int bm = wg / nbn, bn = wg % nbn;

  const int wm = wave >> 1, wn = wave & 1;
  const int lrow = lane >> 3;
  const int lslot = lane & 7;
  const int gslot = lslot ^ lrow;
  const int qlane = lane & 15, kgrp = lane >> 4;

  size_t a_off[4], b_off[4];
  u16 *al_base[4], *bl_base[4];
#pragma unroll
  for (int t = 0; t < 4; ++t) {
    int rr = (wave * 4 + t) * 8 + lrow;
    a_off[t] = (size_t)(bm * 128 + rr) * K + gslot * 8;
    b_off[t] = (size_t)(bn * 128 + rr) * K + gslot * 8;
    al_base[t] = Al + (wave * 4 + t) * 512;
    bl_base[t] = Bl + (wave * 4 + t) * 512;
  }

  f32x4 acc[4][4] = {};
  for (int kt = 0; kt < K; kt += 64) {
#pragma unroll
    for (int t = 0; t < 4; ++t) {
      gload16(A + a_off[t] + kt, al_base[t]);
      gload16(Bt + b_off[t] + kt, bl_base[t]);
    }
    __syncthreads();
#pragma unroll
    for (int kk = 0; kk < 2; ++kk) {
      short8 af[4], bf[4];
#pragma unroll
      for (int mf = 0; mf < 4; ++mf) {
        int row = wm * 64 + mf * 16 + qlane;
        int s = (kk * 4 + kgrp) ^ (row & 7);
        af[mf] = *(const short8*)&Al[row * 64 + s * 8];
      }
#pragma unroll
      for (int nf = 0; nf < 4; ++nf) {
        int row = wn * 64 + nf * 16 + qlane;
        int s = (kk * 4 + kgrp) ^ (row & 7);
        bf[nf] = *(const short8*)&Bl[row * 64 + s * 8];
      }
#pragma unroll
      for (int mf = 0; mf < 4; ++mf)
#pragma unroll
        for (int nf = 0; nf < 4; ++nf)
          acc[mf][nf] = __builtin_amdgcn_mfma_f32_16x16x32_bf16(
              af[mf], bf[nf], acc[mf][nf], 0, 0, 0);
    }
    __syncthreads();
  }

#pragma unroll
  for (int nf = 0; nf < 4; ++nf) {
    int col = bn * 128 + wn * 64 + nf * 16 + qlane;
    float bv = bias[col];
#pragma unroll
    for (int mf = 0; mf < 4; ++mf) {
      int row0 = bm * 128 + wm * 64 + mf * 16 + kgrp * 4;
#pragma unroll
      for (int r = 0; r < 4; ++r) {
        float v = acc[mf][nf][r] + bv;
        if (OUT_BF16)
          ((u16*)Cout)[(size_t)(row0 + r) * N + col] = f2bf(v);
        else
          ((float*)Cout)[(size_t)(row0 + r) * N + col] = v;
      }
    }
  }
}

// ---------------- banded local attention (unchanged, proven) ----------------
__global__ __launch_bounds__(256, 2) void attn_local(
    const u16* __restrict__ qkv, const int* __restrict__ amask,
    u16* __restrict__ aout) {
  __shared__ __align__(16) u16 Kl[192][72];
  __shared__ __align__(16) u16 Vt[64][200];
  __shared__ __align__(16) u16 Pl[4][32][104];

  const int tid = threadIdx.x, wave = tid >> 6, lane = tid & 63;
  const int qlane = lane & 15, kgrp = lane >> 4;
  const int bz = blockIdx.x;
  const int qt = bz & 15, h = (bz >> 4) & 15, b = bz >> 8;
  const int qs0 = qt * 128;
  const int jt = qs0 - 32;
  const size_t rbase = (size_t)b * S_LEN;

  {
    const int r0 = tid >> 3, c0 = (tid & 7) * 8;
#pragma unroll
    for (int p = 0; p < 6; ++p) {
      int row = p * 32 + r0;
      int j = jt + row;
      u16 kv[8], vv[8];
      if (j >= 0 && j < S_LEN) {
        const u16* kp = qkv + (rbase + j) * QKV_LD + HID + h * 64 + c0;
        *(short8*)kv = *(const short8*)kp;
        *(short8*)vv = *(const short8*)(kp + HID);
      } else {
#pragma unroll
        for (int q = 0; q < 8; ++q) { kv[q] = 0; vv[q] = 0; }
      }
      *(short8*)&Kl[row][c0] = *(short8*)kv;
#pragma unroll
      for (int q = 0; q < 8; ++q) Vt[c0 + q][row] = vv[q];
    }
  }

  short8 qf[2][2];
#pragma unroll
  for (int mf = 0; mf < 2; ++mf)
#pragma unroll
    for (int kk = 0; kk < 2; ++kk)
      qf[mf][kk] = *(const short8*)(qkv +
          (rbase + qs0 + wave * 32 + mf * 16 + qlane) * QKV_LD +
          h * 64 + kk * 32 + kgrp * 8);

  __syncthreads();

  f32x4 sc[2][6] = {};
#pragma unroll
  for (int kk = 0; kk < 2; ++kk) {
    short8 kf[6];
#pragma unroll
    for (int nf = 0; nf < 6; ++nf)
      kf[nf] = *(const short8*)&Kl[wave * 32 + nf * 16 + qlane][kk * 32 + kgrp * 8];
#pragma unroll
    for (int mf = 0; mf < 2; ++mf)
#pragma unroll
      for (int nf = 0; nf < 6; ++nf)
        sc[mf][nf] = __builtin_amdgcn_mfma_f32_16x16x32_bf16(
            qf[mf][kk], kf[nf], sc[mf][nf], 0, 0, 0);
  }

  int jcol[6], mv[6];
#pragma unroll
  for (int nf = 0; nf < 6; ++nf) {
    int j = jt + wave * 32 + nf * 16 + qlane;
    jcol[nf] = j;
    mv[nf] = (j >= 0 && j < S_LEN) ? amask[rbase + j] : 0;
  }

  float inv[2][4];
#pragma unroll
  for (int mf = 0; mf < 2; ++mf) {
    const int irow0 = qs0 + wave * 32 + mf * 16 + kgrp * 4;
    float mx[4] = {-1e30f, -1e30f, -1e30f, -1e30f};
#pragma unroll
    for (int r = 0; r < 4; ++r) {
      int i = irow0 + r;
#pragma unroll
      for (int nf = 0; nf < 6; ++nf) {
        int d = i - jcol[nf];
        if (mv[nf] && d >= -32 && d <= 32) mx[r] = fmaxf(mx[r], sc[mf][nf][r]);
      }
    }
#pragma unroll
    for (int m = 1; m < 16; m <<= 1)
#pragma unroll
      for (int r = 0; r < 4; ++r)
        mx[r] = fmaxf(mx[r], __shfl_xor(mx[r], m));
    float sm[4] = {0.f, 0.f, 0.f, 0.f};
#pragma unroll
    for (int r = 0; r < 4; ++r) {
      int i = irow0 + r;
#pragma unroll
      for (int nf = 0; nf < 6; ++nf) {
        int d = i - jcol[nf];
        bool val = mv[nf] && d >= -32 && d <= 32;
        float p = val ? __expf((sc[mf][nf][r] - mx[r]) * 0.125f) : 0.f;
        sc[mf][nf][r] = p;
        sm[r] += p;
      }
    }
#pragma unroll
    for (int m = 1; m < 16; m <<= 1)
#pragma unroll
      for (int r = 0; r < 4; ++r)
        sm[r] += __shfl_xor(sm[r], m);
#pragma unroll
    for (int r = 0; r < 4; ++r)
      inv[mf][r] = sm[r] > 0.f ? 1.f / sm[r] : 0.f;
#pragma unroll
    for (int nf = 0; nf < 6; ++nf)
#pragma unroll
      for (int r = 0; r < 4; ++r)
        Pl[wave][mf * 16 + kgrp * 4 + r][nf * 16 + qlane] = f2bf(sc[mf][nf][r]);
  }
  __syncthreads();

  f32x4 oc[2][4] = {};
#pragma unroll
  for (int ks = 0; ks < 3; ++ks) {
    short8 pa[2], vb[4];
#pragma unroll
    for (int mf = 0; mf < 2; ++mf)
      pa[mf] = *(const short8*)&Pl[wave][mf * 16 + qlane][ks * 32 + kgrp * 8];
#pragma unroll
    for (int nf = 0; nf < 4; ++nf)
      vb[nf] = *(const short8*)&Vt[nf * 16 + qlane][wave * 32 + ks * 32 + kgrp * 8];
#pragma unroll
    for (int mf = 0; mf < 2; ++mf)
#pragma unroll
      for (int nf = 0; nf < 4; ++nf)
        oc[mf][nf] = __builtin_amdgcn_mfma_f32_16x16x32_bf16(
            pa[mf], vb[nf], oc[mf][nf], 0, 0, 0);
  }

#pragma unroll
  for (int mf = 0; mf < 2; ++mf)
#pragma unroll
    for (int nf = 0; nf < 4; ++nf)
#pragma unroll
      for (int r = 0; r < 4; ++r) {
        size_t row = rbase + qs0 + wave * 32 + mf * 16 + kgrp * 4 + r;
        aout[row * HID + h * 64 + nf * 16 + qlane] =
            f2bf(oc[mf][nf][r] * inv[mf][r]);
      }
}

// ---------------- launch ----------------
extern "C" void kernel_launch(void* const* d_in, const int* in_sizes, int n_in,
                              void* d_out, int out_size, void* d_ws, size_t ws_size,
                              hipStream_t stream) {
  const float* x  = (const float*)d_in[0];
  const int* amask = (const int*)d_in[1];
  const float* Wq = (const float*)d_in[2];
  const float* bq = (const float*)d_in[3];
  const float* Wk = (const float*)d_in[4];
  const float* bk = (const float*)d_in[5];
  const float* Wv = (const float*)d_in[6];
  const float* bv = (const float*)d_in[7];
  const float* Wo = (const float*)d_in[8];
  const float* bo = (const float*)d_in[9];
  float* out = (float*)d_out;

  char* w = (char*)d_ws;
  u16* xb    = (u16*)w;   w += (size_t)M_ROWS * HID * 2;
  u16* wqkvt = (u16*)w;   w += (size_t)3072 * 1024 * 2;
  u16* wot   = (u16*)w;   w += (size_t)1024 * 1024 * 2;
  float* bqkv = (float*)w; w += 3072 * 4 + 256;
  u16* qkv   = (u16*)w;   w += (size_t)M_ROWS * 3072 * 2;
  u16* aout  = (u16*)w;   w += (size_t)M_ROWS * HID * 2;

  cvt_bias<<<4097, 256, 0, stream>>>(x, xb, M_ROWS * HID, bq, bk, bv, bqkv);
  pack_weights<<<dim3(32, 32, 4), 256, 0, stream>>>(Wq, Wk, Wv, Wo, wqkvt, wot);

  gemm_k1<<<1024, 256, 0, stream>>>(xb, wqkvt, bqkv, qkv, 3072);
  attn_local<<<1024, 256, 0, stream>>>(qkv, amask, aout);
  gemm_bt<0><<<64 * 8, 256, 0, stream>>>(aout, wot, bo, out, M_ROWS, 1024, 1024);
}